// Round 2
// baseline (361.564 us; speedup 1.0000x reference)
//
#include <hip/hip_runtime.h>
#include <stdint.h>

typedef __attribute__((ext_vector_type(8))) short short8;
typedef __attribute__((ext_vector_type(4))) float floatx4;

#define B_   8
#define H_   16
#define N_   1024
#define D_   64
#define NH_  (B_*H_)      /* 128 heads */
#define ROWS_ (NH_*N_)    /* 131072 rows per tensor */

__device__ __forceinline__ unsigned short f2b(float f) {
    union { float f; unsigned int i; } w; w.f = f;
    unsigned int x = w.i;
    return (unsigned short)((x + 0x7FFFu + ((x >> 16) & 1u)) >> 16);
}

// ---------------------------------------------------------------------------
// Kernel A: L2-normalize q and k rows (D=64), f32 in -> bf16 out.
// 8 lanes per row, 32 rows per 256-thread block.
// ---------------------------------------------------------------------------
__global__ __launch_bounds__(256) void norm_qk(
    const float* __restrict__ q, const float* __restrict__ k,
    unsigned short* __restrict__ qn, unsigned short* __restrict__ kn)
{
    int t = threadIdx.x;
    int g = blockIdx.x * 32 + (t >> 3);
    const float* src; unsigned short* dst; int row;
    if (g < ROWS_) { src = q; dst = qn; row = g; }
    else           { src = k; dst = kn; row = g - ROWS_; }
    int c = (t & 7) * 8;
    float4 v0 = *(const float4*)(src + row * 64 + c);
    float4 v1 = *(const float4*)(src + row * 64 + c + 4);
    float f[8] = {v0.x, v0.y, v0.z, v0.w, v1.x, v1.y, v1.z, v1.w};
    float ss = 0.f;
    #pragma unroll
    for (int j = 0; j < 8; j++) ss += f[j] * f[j];
    ss += __shfl_xor(ss, 1);
    ss += __shfl_xor(ss, 2);
    ss += __shfl_xor(ss, 4);
    float s = 1.0f / fmaxf(sqrtf(ss), 1e-12f);
    short8 vout;
    #pragma unroll
    for (int j = 0; j < 8; j++) ((unsigned short*)&vout)[j] = f2b(f[j] * s);
    *(short8*)(dst + row * 64 + c) = vout;
}

// ---------------------------------------------------------------------------
// Kernel B: per-head transpose v[n][d] -> vt[d][n], f32 in -> bf16 out.
// One block transposes a 64-key x 64-dim tile through LDS.
// ---------------------------------------------------------------------------
__global__ __launch_bounds__(256) void transpose_v(
    const float* __restrict__ v, unsigned short* __restrict__ vt)
{
    __shared__ float tile[64][65];   // +1 pad breaks bank periodicity
    int head = blockIdx.x >> 4;
    int kb   = (blockIdx.x & 15) * 64;
    int t = threadIdx.x;
    #pragma unroll
    for (int it = 0; it < 2; it++) {
        int key = it * 32 + (t >> 3);
        int c8  = (t & 7) * 8;
        float4 a = *(const float4*)(v + (head * N_ + kb + key) * 64 + c8);
        float4 b = *(const float4*)(v + (head * N_ + kb + key) * 64 + c8 + 4);
        tile[key][c8 + 0] = a.x; tile[key][c8 + 1] = a.y;
        tile[key][c8 + 2] = a.z; tile[key][c8 + 3] = a.w;
        tile[key][c8 + 4] = b.x; tile[key][c8 + 5] = b.y;
        tile[key][c8 + 6] = b.z; tile[key][c8 + 7] = b.w;
    }
    __syncthreads();
    #pragma unroll
    for (int it = 0; it < 2; it++) {
        int d  = it * 32 + (t >> 3);
        int n8 = (t & 7) * 8;
        short8 vout;
        #pragma unroll
        for (int j = 0; j < 8; j++) ((unsigned short*)&vout)[j] = f2b(tile[n8 + j][d]);
        *(short8*)(vt + (head * 64 + d) * N_ + kb + n8) = vout;
    }
}

// ---------------------------------------------------------------------------
// Kernel C: attention. 1 wave = 16 queries; 4 waves/block; 2048 blocks.
// S = Qn . Kn^T via mfma_f32_16x16x32_bf16 (K=64 in 2 steps);
// p = exp(s) (logits in [-1,1] -> no max subtraction needed);
// P transposed C-layout -> A-layout through per-wave LDS tile;
// O += P.V via mfma with vt giving contiguous B-fragments; final O/l -> f32.
// ---------------------------------------------------------------------------
__global__ __launch_bounds__(256) void attn(
    const unsigned short* __restrict__ qn, const unsigned short* __restrict__ kn,
    const unsigned short* __restrict__ vt, float* __restrict__ out)
{
    __shared__ __align__(16) unsigned short p_lds[4][16][40]; // pad 8 keeps 16B align
    int head = blockIdx.x >> 4;
    int qt   = blockIdx.x & 15;
    int wave = threadIdx.x >> 6;
    int lane = threadIdx.x & 63;
    int m = lane & 15, quad = lane >> 4;
    int q0 = qt * 64 + wave * 16;

    // Q A-fragments: A[m=lane&15][k=quad*8+j], contiguous 16B loads
    const unsigned short* qbase = qn + (head * N_ + q0 + m) * 64 + quad * 8;
    short8 aq0 = *(const short8*)(qbase);
    short8 aq1 = *(const short8*)(qbase + 32);

    floatx4 oacc[4];
    #pragma unroll
    for (int n = 0; n < 4; n++) oacc[n] = (floatx4){0.f, 0.f, 0.f, 0.f};
    float l4[4] = {0.f, 0.f, 0.f, 0.f};

    const unsigned short* kbase = kn + head * N_ * 64;
    const unsigned short* vbase = vt + head * 64 * N_;

    for (int kc = 0; kc < N_; kc += 32) {
        // ---- QK^T: two 16-key subtiles ----
        #pragma unroll
        for (int st = 0; st < 2; st++) {
            const unsigned short* kp = kbase + (kc + st * 16 + m) * 64 + quad * 8;
            short8 bk0 = *(const short8*)(kp);
            short8 bk1 = *(const short8*)(kp + 32);
            floatx4 s = (floatx4){0.f, 0.f, 0.f, 0.f};
            s = __builtin_amdgcn_mfma_f32_16x16x32_bf16(aq0, bk0, s, 0, 0, 0);
            s = __builtin_amdgcn_mfma_f32_16x16x32_bf16(aq1, bk1, s, 0, 0, 0);
            // C layout: row = quad*4+r, col = m
            #pragma unroll
            for (int r = 0; r < 4; r++) {
                float e = __expf(s[r]);
                l4[r] += e;
                p_lds[wave][quad * 4 + r][st * 16 + m] = f2b(e);
            }
        }
        // ---- P: C-layout -> A-layout via LDS (in-wave ordering only) ----
        short8 pa = *(const short8*)&p_lds[wave][m][quad * 8];
        // ---- PV: 4 dim-tiles of 16 ----
        #pragma unroll
        for (int n = 0; n < 4; n++) {
            short8 bv = *(const short8*)(vbase + (n * 16 + m) * N_ + kc + quad * 8);
            oacc[n] = __builtin_amdgcn_mfma_f32_16x16x32_bf16(pa, bv, oacc[n], 0, 0, 0);
        }
    }

    // denominator: reduce across the 16 lanes sharing this quad's rows
    #pragma unroll
    for (int r = 0; r < 4; r++) {
        float s = l4[r];
        s += __shfl_xor(s, 1);
        s += __shfl_xor(s, 2);
        s += __shfl_xor(s, 4);
        s += __shfl_xor(s, 8);
        l4[r] = s;
    }

    int b = head >> 4, h = head & 15;
    #pragma unroll
    for (int n = 0; n < 4; n++) {
        #pragma unroll
        for (int r = 0; r < 4; r++) {
            int qrow = q0 + quad * 4 + r;
            int idx = (b * N_ + qrow) * (H_ * D_) + h * 64 + n * 16 + m;
            out[idx] = oacc[n][r] / l4[r];
        }
    }
}

extern "C" void kernel_launch(void* const* d_in, const int* in_sizes, int n_in,
                              void* d_out, int out_size, void* d_ws, size_t ws_size,
                              hipStream_t stream) {
    const float* q = (const float*)d_in[0];
    const float* k = (const float*)d_in[1];
    const float* v = (const float*)d_in[2];
    float* out = (float*)d_out;

    unsigned short* qn = (unsigned short*)d_ws;          // 16 MB
    unsigned short* kn = qn + (size_t)ROWS_ * 64;        // 16 MB
    unsigned short* vt = kn + (size_t)ROWS_ * 64;        // 16 MB

    hipLaunchKernelGGL(norm_qk, dim3(2 * ROWS_ / 32), dim3(256), 0, stream, q, k, qn, kn);
    hipLaunchKernelGGL(transpose_v, dim3(NH_ * 16), dim3(256), 0, stream, v, vt);
    hipLaunchKernelGGL(attn, dim3(NH_ * 16), dim3(256), 0, stream, qn, kn, vt, out);
}

// Round 3
// 203.074 us; speedup vs baseline: 1.7805x; 1.7805x over previous
//
#include <hip/hip_runtime.h>
#include <stdint.h>

typedef __attribute__((ext_vector_type(8))) short short8;
typedef __attribute__((ext_vector_type(4))) float floatx4;

#define B_   8
#define H_   16
#define N_   1024
#define D_   64
#define NH_  (B_*H_)      /* 128 heads */
#define ROWS_ (NH_*N_)    /* 131072 rows per tensor */
#define LOG2E 1.44269504088896340736f

__device__ __forceinline__ unsigned short f2b(float f) {   // RNE bf16 (prep)
    union { float f; unsigned int i; } w; w.f = f;
    unsigned int x = w.i;
    return (unsigned short)((x + 0x7FFFu + ((x >> 16) & 1u)) >> 16);
}

// pack two positive f32 -> bf16x2 (round half-up; p=exp(s)>0 so safe)
__device__ __forceinline__ unsigned int pk2(float a, float b) {
    unsigned int ua = __float_as_uint(a) + 0x8000u;
    unsigned int ub = __float_as_uint(b) + 0x8000u;
    return __builtin_amdgcn_perm(ub, ua, 0x07060302);  // (bf(b)<<16)|bf(a)
}

__device__ __forceinline__ void load_lds16(const void* g, void* l) {
    __builtin_amdgcn_global_load_lds(
        (const __attribute__((address_space(1))) void*)g,
        (__attribute__((address_space(3))) void*)l, 16, 0, 0);
}

// ---------------------------------------------------------------------------
// Kernel A: L2-normalize q and k rows (D=64), f32 in -> bf16 out.
// q additionally scaled by log2(e) so attn can use raw exp2.
// ---------------------------------------------------------------------------
__global__ __launch_bounds__(256) void norm_qk(
    const float* __restrict__ q, const float* __restrict__ k,
    unsigned short* __restrict__ qn, unsigned short* __restrict__ kn)
{
    int t = threadIdx.x;
    int g = blockIdx.x * 32 + (t >> 3);
    const float* src; unsigned short* dst; int row; float scale;
    if (g < ROWS_) { src = q; dst = qn; row = g;          scale = LOG2E; }
    else           { src = k; dst = kn; row = g - ROWS_;  scale = 1.0f;  }
    int c = (t & 7) * 8;
    float4 v0 = *(const float4*)(src + row * 64 + c);
    float4 v1 = *(const float4*)(src + row * 64 + c + 4);
    float f[8] = {v0.x, v0.y, v0.z, v0.w, v1.x, v1.y, v1.z, v1.w};
    float ss = 0.f;
    #pragma unroll
    for (int j = 0; j < 8; j++) ss += f[j] * f[j];
    ss += __shfl_xor(ss, 1);
    ss += __shfl_xor(ss, 2);
    ss += __shfl_xor(ss, 4);
    float s = scale / fmaxf(sqrtf(ss), 1e-12f);
    short8 vout;
    #pragma unroll
    for (int j = 0; j < 8; j++) ((unsigned short*)&vout)[j] = f2b(f[j] * s);
    *(short8*)(dst + row * 64 + c) = vout;
}

// ---------------------------------------------------------------------------
// Kernel B: per-head transpose v[n][d] -> vt[d][kperm(n)], f32 -> bf16.
// Key order permuted within each 64-key block so the attn PV B-fragment
// (composite 2x16-key K=32 MFMA) is one contiguous 16B read:
//   phys = g*32 + quad*8 + h*4 + j  <->  logical = g*32 + h*16 + quad*4 + j
// ---------------------------------------------------------------------------
__global__ __launch_bounds__(256) void transpose_v(
    const float* __restrict__ v, unsigned short* __restrict__ vt)
{
    __shared__ float tile[64][65];
    int head = blockIdx.x >> 4;
    int kb   = (blockIdx.x & 15) * 64;
    int t = threadIdx.x;
    #pragma unroll
    for (int it = 0; it < 2; it++) {
        int key = it * 32 + (t >> 3);
        int c8  = (t & 7) * 8;
        float4 a = *(const float4*)(v + ((size_t)head * N_ + kb + key) * 64 + c8);
        float4 b = *(const float4*)(v + ((size_t)head * N_ + kb + key) * 64 + c8 + 4);
        tile[key][c8 + 0] = a.x; tile[key][c8 + 1] = a.y;
        tile[key][c8 + 2] = a.z; tile[key][c8 + 3] = a.w;
        tile[key][c8 + 4] = b.x; tile[key][c8 + 5] = b.y;
        tile[key][c8 + 6] = b.z; tile[key][c8 + 7] = b.w;
    }
    __syncthreads();
    #pragma unroll
    for (int it = 0; it < 2; it++) {
        int d  = it * 32 + (t >> 3);
        int pb = (t & 7) * 8;                  // phys col base (multiple of 8)
        int g = pb >> 5, quadp = (pb >> 3) & 3;
        short8 vout;
        #pragma unroll
        for (int j = 0; j < 8; j++) {
            int kap = g * 32 + (j >> 2) * 16 + quadp * 4 + (j & 3);
            ((unsigned short*)&vout)[j] = f2b(tile[kap][d]);
        }
        *(short8*)(vt + ((size_t)head * 64 + d) * N_ + kb + pb) = vout;
    }
}

// ---------------------------------------------------------------------------
// Kernel C: attention. 256 threads = 4 waves; wave = 64 queries (4 m-tiles);
// block = 256 queries; grid = 128 heads * 4 = 512 (XCD-swizzled).
// K/V staged in LDS (64-key chunks, double-buffered, global_load_lds w=16,
// XOR col-swizzle). S^T = K.Q^T so exp(S^T) is directly the PV A-fragment.
// ---------------------------------------------------------------------------
__global__ __launch_bounds__(256, 2) void attn(
    const unsigned short* __restrict__ qn, const unsigned short* __restrict__ kn,
    const unsigned short* __restrict__ vt, float* __restrict__ out)
{
    __shared__ __align__(16) unsigned short ks[2][64 * 64];
    __shared__ __align__(16) unsigned short vs[2][64 * 64];

    int bid = blockIdx.x;
    int xcd = bid & 7, rest = bid >> 3;
    int qt = rest & 3;
    int head = (rest >> 2) * 8 + xcd;          // 4 blocks of a head share an XCD
    int tid = threadIdx.x, w = tid >> 6, lane = tid & 63;
    int lam = lane & 15, quad = lane >> 4;
    int sw = lam & 7;                          // read-side swizzle key
    int q0 = qt * 256 + w * 64;

    const unsigned short* qh = qn + ((size_t)head * N_ + q0) * 64;
    const char* khb = (const char*)(kn + (size_t)head * N_ * 64);
    const char* vhb = (const char*)(vt + (size_t)head * 64 * N_);

    // Q fragments (B-operand layout): aq[t][h] = Q[q0+t*16+lam][h*32+quad*8 ..]
    short8 aq[4][2];
    #pragma unroll
    for (int t = 0; t < 4; t++)
        #pragma unroll
        for (int h = 0; h < 2; h++)
            aq[t][h] = *(const short8*)(qh + (t * 16 + lam) * 64 + h * 32 + quad * 8);

    floatx4 oacc[4][4];
    #pragma unroll
    for (int t = 0; t < 4; t++)
        #pragma unroll
        for (int dt = 0; dt < 4; dt++) oacc[t][dt] = (floatx4){0.f, 0.f, 0.f, 0.f};
    float l[4] = {0.f, 0.f, 0.f, 0.f};

    // stage chunk ck into buffer buf: K rows contiguous, V rows strided;
    // global-side XOR swizzle so LDS slot (row, cb) holds column block cb^(row&7)
    auto stage = [&](int buf, int ck) {
        #pragma unroll
        for (int i = 0; i < 2; i++) {
            int flat = w * 2048 + i * 1024 + lane * 16;
            int row = flat >> 7;
            int cb  = (flat >> 4) & 7;
            int swz = ((cb ^ (row & 7)) << 4);
            const void* gk = khb + (size_t)ck * 8192 + (flat & ~127) + swz;
            const void* gv = vhb + (size_t)row * 2048 + ck * 128 + swz;
            void* lk = (void*)&ks[buf][(w * 2048 + i * 1024) >> 1];
            void* lv = (void*)&vs[buf][(w * 2048 + i * 1024) >> 1];
            load_lds16(gk, lk);
            load_lds16(gv, lv);
        }
    };

    stage(0, 0);

    for (int c = 0; c < 16; ++c) {
        __syncthreads();                       // chunk c resident; buf^1 free
        if (c + 1 < 16) stage((c + 1) & 1, c + 1);
        const unsigned short* ksb = &ks[c & 1][0];
        const unsigned short* vsb = &vs[c & 1][0];

        #pragma unroll
        for (int g = 0; g < 2; g++) {
            // ---- S^T for 2 subtiles (32 keys): A=K-frag, B=Q-frag ----
            floatx4 s[4][2];
            #pragma unroll
            for (int s2 = 0; s2 < 2; s2++) {
                int st = g * 2 + s2;
                short8 bk0 = *(const short8*)(ksb + (st * 16 + lam) * 64 + (((0 + quad) ^ sw) << 3));
                short8 bk1 = *(const short8*)(ksb + (st * 16 + lam) * 64 + (((4 + quad) ^ sw) << 3));
                #pragma unroll
                for (int t = 0; t < 4; t++) {
                    floatx4 acc = (floatx4){0.f, 0.f, 0.f, 0.f};
                    acc = __builtin_amdgcn_mfma_f32_16x16x32_bf16(bk0, aq[t][0], acc, 0, 0, 0);
                    acc = __builtin_amdgcn_mfma_f32_16x16x32_bf16(bk1, aq[t][1], acc, 0, 0, 0);
                    s[t][s2] = acc;
                }
            }
            // ---- exp2 + pack: S^T C-layout IS the PV A-fragment layout ----
            short8 pa[4];
            #pragma unroll
            for (int t = 0; t < 4; t++) {
                float e00 = exp2f(s[t][0][0]), e01 = exp2f(s[t][0][1]);
                float e02 = exp2f(s[t][0][2]), e03 = exp2f(s[t][0][3]);
                float e10 = exp2f(s[t][1][0]), e11 = exp2f(s[t][1][1]);
                float e12 = exp2f(s[t][1][2]), e13 = exp2f(s[t][1][3]);
                l[t] += ((e00 + e01) + (e02 + e03)) + ((e10 + e11) + (e12 + e13));
                union { unsigned int u[4]; short8 s8; } pk;
                pk.u[0] = pk2(e00, e01); pk.u[1] = pk2(e02, e03);
                pk.u[2] = pk2(e10, e11); pk.u[3] = pk2(e12, e13);
                pa[t] = pk.s8;
            }
            // ---- PV: O += P.V over these 32 keys (permuted V -> b128 frag) ----
            #pragma unroll
            for (int dt = 0; dt < 4; dt++) {
                short8 bv = *(const short8*)(vsb + (dt * 16 + lam) * 64 + (((g * 4 + quad) ^ sw) << 3));
                #pragma unroll
                for (int t = 0; t < 4; t++)
                    oacc[t][dt] = __builtin_amdgcn_mfma_f32_16x16x32_bf16(pa[t], bv, oacc[t][dt], 0, 0, 0);
            }
        }
    }

    // ---- epilogue: reduce l across quads, divide, store f32 ----
    int b = head >> 4, hh = head & 15;
    #pragma unroll
    for (int t = 0; t < 4; t++) {
        float lr = l[t];
        lr += __shfl_xor(lr, 16);
        lr += __shfl_xor(lr, 32);
        float rl = 1.0f / lr;                  // lane lam: 1/l for query t*16+lam
        float rq[4];
        #pragma unroll
        for (int r = 0; r < 4; r++) rq[r] = __shfl(rl, quad * 4 + r);
        float* ob = out + ((size_t)b * N_ + q0 + t * 16) * (H_ * D_) + hh * 64;
        #pragma unroll
        for (int dt = 0; dt < 4; dt++)
            #pragma unroll
            for (int r = 0; r < 4; r++)
                ob[(quad * 4 + r) * (H_ * D_) + dt * 16 + lam] = oacc[t][dt][r] * rq[r];
    }
}

extern "C" void kernel_launch(void* const* d_in, const int* in_sizes, int n_in,
                              void* d_out, int out_size, void* d_ws, size_t ws_size,
                              hipStream_t stream) {
    const float* q = (const float*)d_in[0];
    const float* k = (const float*)d_in[1];
    const float* v = (const float*)d_in[2];
    float* out = (float*)d_out;

    unsigned short* qn = (unsigned short*)d_ws;          // 16 MB
    unsigned short* kn = qn + (size_t)ROWS_ * 64;        // 16 MB
    unsigned short* vt = kn + (size_t)ROWS_ * 64;        // 16 MB

    hipLaunchKernelGGL(norm_qk, dim3(2 * ROWS_ / 32), dim3(256), 0, stream, q, k, qn, kn);
    hipLaunchKernelGGL(transpose_v, dim3(NH_ * 16), dim3(256), 0, stream, v, vt);
    hipLaunchKernelGGL(attn, dim3(NH_ * 4), dim3(256), 0, stream, qn, kn, vt, out);
}

// Round 4
// 167.715 us; speedup vs baseline: 2.1558x; 1.2108x over previous
//
#include <hip/hip_runtime.h>
#include <stdint.h>

typedef __attribute__((ext_vector_type(8))) short short8;
typedef __attribute__((ext_vector_type(4))) float floatx4;

#define B_   8
#define H_   16
#define N_   1024
#define D_   64
#define NH_  (B_*H_)
#define LOG2E 1.44269504088896340736f

#define KS_STRIDE 72   /* shorts: 144B rows = 9*16B -> b128 aligned; frag reads phase-optimal */
#define VS_STRIDE 68   /* shorts: 136B rows; with bit-1 XOR swizzle the u16 gather is conflict-free */

extern "C" {
__device__ float __ocml_native_exp2_f32(float);
__device__ float __ocml_native_rsqrt_f32(float);
}

// pack two f32 -> bf16x2 (round-half-up on magnitude; fine for our ranges)
__device__ __forceinline__ unsigned int pk2(float a, float b) {
    unsigned int ua = __float_as_uint(a) + 0x8000u;
    unsigned int ub = __float_as_uint(b) + 0x8000u;
    return __builtin_amdgcn_perm(ub, ua, 0x07060302);  // (bf(b)<<16)|bf(a)
}

// ---------------------------------------------------------------------------
// Fully fused cosine attention. 256 threads = 4 waves; wave = 64 queries;
// block = 256 queries; grid = 128 heads * 4 = 512 (XCD-swizzled: the 4 blocks
// of a head share an XCD so K/V f32 re-reads hit that XCD's L2).
// Per 64-key chunk: load K/V f32 (coalesced 64B instrs), normalize K rows,
// convert to bf16, stage into double-buffered LDS; S^T = K.Qn^T via MFMA so
// exp(S^T) is directly the PV A-fragment; PV B-frag gathered from LDS.
// ---------------------------------------------------------------------------
__global__ __launch_bounds__(256, 2) void attn_fused(
    const float* __restrict__ q, const float* __restrict__ k,
    const float* __restrict__ v, float* __restrict__ out)
{
    __shared__ __align__(16) unsigned short ks[2][64 * KS_STRIDE];
    __shared__ __align__(16) unsigned short vs[2][64 * VS_STRIDE];

    const int bid = blockIdx.x;
    const int xcd = bid & 7, rest = bid >> 3;
    const int qt = rest & 3;
    const int head = (rest >> 2) * 8 + xcd;
    const int tid = threadIdx.x, w = tid >> 6, lane = tid & 63;
    const int lam = lane & 15, quad = lane >> 4;
    const int q0 = qt * 256 + w * 64;

    const float* qh = q + ((size_t)head * N_ + q0) * D_;
    const float* kh = k + (size_t)head * N_ * D_;
    const float* vh = v + (size_t)head * N_ * D_;

    // ---- Q: load f32, L2-normalize (x log2e), pack to bf16 B-frags ----
    short8 aq[4][2];
    #pragma unroll
    for (int t = 0; t < 4; t++) {
        const float* qr = qh + (t * 16 + lam) * D_ + quad * 8;
        float4 f0 = *(const float4*)(qr);
        float4 f1 = *(const float4*)(qr + 4);
        float4 f2 = *(const float4*)(qr + 32);
        float4 f3 = *(const float4*)(qr + 36);
        float ss = f0.x*f0.x + f0.y*f0.y + f0.z*f0.z + f0.w*f0.w
                 + f1.x*f1.x + f1.y*f1.y + f1.z*f1.z + f1.w*f1.w
                 + f2.x*f2.x + f2.y*f2.y + f2.z*f2.z + f2.w*f2.w
                 + f3.x*f3.x + f3.y*f3.y + f3.z*f3.z + f3.w*f3.w;
        ss += __shfl_xor(ss, 16);          // 4 quads of same lam cover dims 0..63
        ss += __shfl_xor(ss, 32);
        float sc = LOG2E * __ocml_native_rsqrt_f32(ss);
        union { unsigned int u[4]; short8 s8; } p0, p1;
        p0.u[0] = pk2(f0.x*sc, f0.y*sc); p0.u[1] = pk2(f0.z*sc, f0.w*sc);
        p0.u[2] = pk2(f1.x*sc, f1.y*sc); p0.u[3] = pk2(f1.z*sc, f1.w*sc);
        p1.u[0] = pk2(f2.x*sc, f2.y*sc); p1.u[1] = pk2(f2.z*sc, f2.w*sc);
        p1.u[2] = pk2(f3.x*sc, f3.y*sc); p1.u[3] = pk2(f3.z*sc, f3.w*sc);
        aq[t][0] = p0.s8; aq[t][1] = p1.s8;
    }

    floatx4 oacc[4][4];
    #pragma unroll
    for (int t = 0; t < 4; t++)
        #pragma unroll
        for (int dt = 0; dt < 4; dt++) oacc[t][dt] = (floatx4){0.f, 0.f, 0.f, 0.f};
    float l[4] = {0.f, 0.f, 0.f, 0.f};

    // staging geometry: thread owns row srow, float cols scb+16*i .. +3 (i=0..3)
    const int srow = w * 16 + (lane >> 2);     // 0..63 within chunk
    const int scb  = (lane & 3) * 4;           // per-instr 64B-contiguous across 4 lanes
    const int vswz = ((srow >> 1) & 1) << 1;   // V d-swizzle (bit1) -> conflict-free gather

    float4 kx[4], vx[4];
    auto gload = [&](int ck) {
        const float* kp = kh + ((size_t)(ck * 64 + srow)) * D_ + scb;
        const float* vp = vh + ((size_t)(ck * 64 + srow)) * D_ + scb;
        #pragma unroll
        for (int i = 0; i < 4; i++) {
            kx[i] = *(const float4*)(kp + 16 * i);
            vx[i] = *(const float4*)(vp + 16 * i);
        }
    };
    auto stage = [&](int buf) {
        float ss = 0.f;
        #pragma unroll
        for (int i = 0; i < 4; i++)
            ss += kx[i].x*kx[i].x + kx[i].y*kx[i].y + kx[i].z*kx[i].z + kx[i].w*kx[i].w;
        ss += __shfl_xor(ss, 1);               // 4 lanes of same row cover dims 0..63
        ss += __shfl_xor(ss, 2);
        float sc = __ocml_native_rsqrt_f32(ss);
        #pragma unroll
        for (int i = 0; i < 4; i++) {
            int c = scb + 16 * i;
            unsigned int k0 = pk2(kx[i].x*sc, kx[i].y*sc);
            unsigned int k1 = pk2(kx[i].z*sc, kx[i].w*sc);
            *(uint2*)(&ks[buf][srow * KS_STRIDE + c]) = make_uint2(k0, k1);  // b64, phase-optimal
            unsigned int v0 = pk2(vx[i].x, vx[i].y);
            unsigned int v1 = pk2(vx[i].z, vx[i].w);
            *(unsigned int*)(&vs[buf][srow * VS_STRIDE + ((c + 0) ^ vswz)]) = v0;
            *(unsigned int*)(&vs[buf][srow * VS_STRIDE + ((c + 2) ^ vswz)]) = v1;
        }
    };

    auto compute = [&](int buf) {
        const unsigned short* ksb = &ks[buf][0];
        const unsigned short* vsb = &vs[buf][0];
        #pragma unroll
        for (int g = 0; g < 2; g++) {
            // ---- S^T for 32 keys: A = K-frag (LDS b128), B = Q-frag (regs) ----
            floatx4 s[4][2];
            #pragma unroll
            for (int s2 = 0; s2 < 2; s2++) {
                int st = g * 2 + s2;
                short8 bk0 = *(const short8*)(ksb + (st * 16 + lam) * KS_STRIDE + quad * 8);
                short8 bk1 = *(const short8*)(ksb + (st * 16 + lam) * KS_STRIDE + 32 + quad * 8);
                #pragma unroll
                for (int t = 0; t < 4; t++) {
                    floatx4 acc = (floatx4){0.f, 0.f, 0.f, 0.f};
                    acc = __builtin_amdgcn_mfma_f32_16x16x32_bf16(bk0, aq[t][0], acc, 0, 0, 0);
                    acc = __builtin_amdgcn_mfma_f32_16x16x32_bf16(bk1, aq[t][1], acc, 0, 0, 0);
                    s[t][s2] = acc;
                }
            }
            // ---- exp2 + pack: S^T C-layout IS the PV A-fragment layout ----
            short8 pa[4];
            #pragma unroll
            for (int t = 0; t < 4; t++) {
                float e00 = __ocml_native_exp2_f32(s[t][0][0]);
                float e01 = __ocml_native_exp2_f32(s[t][0][1]);
                float e02 = __ocml_native_exp2_f32(s[t][0][2]);
                float e03 = __ocml_native_exp2_f32(s[t][0][3]);
                float e10 = __ocml_native_exp2_f32(s[t][1][0]);
                float e11 = __ocml_native_exp2_f32(s[t][1][1]);
                float e12 = __ocml_native_exp2_f32(s[t][1][2]);
                float e13 = __ocml_native_exp2_f32(s[t][1][3]);
                l[t] += ((e00 + e01) + (e02 + e03)) + ((e10 + e11) + (e12 + e13));
                union { unsigned int u[4]; short8 s8; } pk;
                pk.u[0] = pk2(e00, e01); pk.u[1] = pk2(e02, e03);
                pk.u[2] = pk2(e10, e11); pk.u[3] = pk2(e12, e13);
                pa[t] = pk.s8;
            }
            // ---- PV B-frag: u16 gather (conflict-free by construction) ----
            #pragma unroll
            for (int dt = 0; dt < 4; dt++) {
                union { unsigned short h[8]; short8 s8; } bv;
                #pragma unroll
                for (int j = 0; j < 8; j++) {
                    int key = g * 32 + ((j >> 2) << 4) + quad * 4 + (j & 3);
                    int dsw = ((j >> 1) & 1) << 1;   // == ((key>>1)&1)<<1
                    bv.h[j] = vsb[key * VS_STRIDE + ((dt * 16 + lam) ^ dsw)];
                }
                #pragma unroll
                for (int t = 0; t < 4; t++)
                    oacc[t][dt] = __builtin_amdgcn_mfma_f32_16x16x32_bf16(pa[t], bv.s8, oacc[t][dt], 0, 0, 0);
            }
        }
    };

    // ---- software-pipelined chunk loop: 1 barrier per chunk ----
    gload(0);
    stage(0);
    __syncthreads();
    for (int c = 0; c < 16; ++c) {
        int buf = c & 1;
        if (c < 15) gload(c + 1);      // regs prefetch overlaps compute
        compute(buf);
        if (c < 15) stage(buf ^ 1);    // waits on prefetch, writes other buffer
        __syncthreads();
    }

    // ---- epilogue: reduce l across quads, divide, store f32 ----
    const int b = head >> 4, hh = head & 15;
    #pragma unroll
    for (int t = 0; t < 4; t++) {
        float lr = l[t];
        lr += __shfl_xor(lr, 16);
        lr += __shfl_xor(lr, 32);
        float rl = 1.0f / lr;                    // lane lam holds 1/l for query t*16+lam
        float rq[4];
        #pragma unroll
        for (int r = 0; r < 4; r++) rq[r] = __shfl(rl, quad * 4 + r);
        float* ob = out + ((size_t)b * N_ + q0 + t * 16) * (H_ * D_) + hh * 64;
        #pragma unroll
        for (int dt = 0; dt < 4; dt++)
            #pragma unroll
            for (int r = 0; r < 4; r++)
                ob[(quad * 4 + r) * (H_ * D_) + dt * 16 + lam] = oacc[t][dt][r] * rq[r];
    }
}

extern "C" void kernel_launch(void* const* d_in, const int* in_sizes, int n_in,
                              void* d_out, int out_size, void* d_ws, size_t ws_size,
                              hipStream_t stream) {
    const float* q = (const float*)d_in[0];
    const float* k = (const float*)d_in[1];
    const float* v = (const float*)d_in[2];
    float* out = (float*)d_out;
    (void)d_ws; (void)ws_size;
    hipLaunchKernelGGL(attn_fused, dim3(NH_ * 4), dim3(256), 0, stream, q, k, v, out);
}

// Round 5
// 164.461 us; speedup vs baseline: 2.1985x; 1.0198x over previous
//
#include <hip/hip_runtime.h>
#include <stdint.h>

typedef __attribute__((ext_vector_type(8))) short short8;
typedef __attribute__((ext_vector_type(4))) float floatx4;

#define B_   8
#define H_   16
#define N_   1024
#define D_   64
#define NH_  (B_*H_)
#define LOG2E 1.44269504088896340736f

extern "C" {
__device__ float __ocml_native_exp2_f32(float);
__device__ float __ocml_native_rsqrt_f32(float);
}

// pack two f32 -> bf16x2 (round-half-up on magnitude; fine for our ranges)
__device__ __forceinline__ unsigned int pk2(float a, float b) {
    unsigned int ua = __float_as_uint(a) + 0x8000u;
    unsigned int ub = __float_as_uint(b) + 0x8000u;
    return __builtin_amdgcn_perm(ub, ua, 0x07060302);  // (bf(b)<<16)|bf(a)
}

// ---------------------------------------------------------------------------
// Fully fused cosine attention. 256 threads = 4 waves; wave = 64 queries;
// block = 256 queries; grid = 128 heads * 4 (XCD-swizzled).
// LDS discipline (round-3-verified, 0 conflicts): stride-64 rows, XOR swizzle
// cb^(row&7) on 16B blocks, ALL LDS accesses are 16B-aligned b128.
//   ks[key][d]  : K chunk, bf16, row-normalized
//   vt[d][key]  : V chunk TRANSPOSED, key order permuted by
//                 L(cb,j) = (cb>>2)*32 + (cb&3)*4 + (j>>2)*16 + (j&3)
//                 so the PV B-fragment is one b128 read.
// S^T = K.Qn^T via MFMA so exp(S^T) is directly the PV A-fragment.
// ---------------------------------------------------------------------------
__global__ __launch_bounds__(256, 2) void attn_fused(
    const float* __restrict__ q, const float* __restrict__ k,
    const float* __restrict__ v, float* __restrict__ out)
{
    __shared__ __align__(16) unsigned short ks[2][64 * 64];
    __shared__ __align__(16) unsigned short vt[2][64 * 64];

    const int bid = blockIdx.x;
    const int xcd = bid & 7, rest = bid >> 3;
    const int qt = rest & 3;
    const int head = (rest >> 2) * 8 + xcd;    // 4 blocks of a head share an XCD
    const int tid = threadIdx.x, w = tid >> 6, lane = tid & 63;
    const int lam = lane & 15, quad = lane >> 4;
    const int sw = lam & 7;                    // frag-read swizzle key
    const int q0 = qt * 256 + w * 64;

    const float* qh = q + ((size_t)head * N_ + q0) * D_;
    const float* kh = k + (size_t)head * N_ * D_;
    const float* vh = v + (size_t)head * N_ * D_;

    // ---- Q: load f32, L2-normalize (x log2e), pack to bf16 B-frags ----
    short8 aq[4][2];
    #pragma unroll
    for (int t = 0; t < 4; t++) {
        const float* qr = qh + (t * 16 + lam) * D_ + quad * 8;
        float4 f0 = *(const float4*)(qr);
        float4 f1 = *(const float4*)(qr + 4);
        float4 f2 = *(const float4*)(qr + 32);
        float4 f3 = *(const float4*)(qr + 36);
        float ss = f0.x*f0.x + f0.y*f0.y + f0.z*f0.z + f0.w*f0.w
                 + f1.x*f1.x + f1.y*f1.y + f1.z*f1.z + f1.w*f1.w
                 + f2.x*f2.x + f2.y*f2.y + f2.z*f2.z + f2.w*f2.w
                 + f3.x*f3.x + f3.y*f3.y + f3.z*f3.z + f3.w*f3.w;
        ss += __shfl_xor(ss, 16);      // 4 quads of same lam cover dims 0..63
        ss += __shfl_xor(ss, 32);
        float sc = LOG2E * __ocml_native_rsqrt_f32(ss);
        union { unsigned int u[4]; short8 s8; } p0, p1;
        p0.u[0] = pk2(f0.x*sc, f0.y*sc); p0.u[1] = pk2(f0.z*sc, f0.w*sc);
        p0.u[2] = pk2(f1.x*sc, f1.y*sc); p0.u[3] = pk2(f1.z*sc, f1.w*sc);
        p1.u[0] = pk2(f2.x*sc, f2.y*sc); p1.u[1] = pk2(f2.z*sc, f2.w*sc);
        p1.u[2] = pk2(f3.x*sc, f3.y*sc); p1.u[3] = pk2(f3.z*sc, f3.w*sc);
        aq[t][0] = p0.s8; aq[t][1] = p1.s8;
    }

    floatx4 oacc[4][4];
    #pragma unroll
    for (int t = 0; t < 4; t++)
        #pragma unroll
        for (int dt = 0; dt < 4; dt++) oacc[t][dt] = (floatx4){0.f, 0.f, 0.f, 0.f};
    float l[4] = {0.f, 0.f, 0.f, 0.f};

    // ---- staging maps ----
    // K: thread owns key srow, logical d-blocks (lane&3)+4i (8 d each)
    const int srow = w * 16 + (lane >> 2);
    const int kd   = (lane & 3) * 8;
    const int ksw  = srow & 7;
    // V^T: thread owns d = lane, phys key-blocks cb = 2w, 2w+1
    const int vsw  = lane & 7;
    const int cb0  = 2 * w;

    float4 kx[4];
    float  vr[2][8];

    auto gload = [&](int ck) {
        const float* kp = kh + ((size_t)(ck * 64 + srow)) * D_ + kd;
        kx[0] = *(const float4*)(kp);
        kx[1] = *(const float4*)(kp + 4);
        kx[2] = *(const float4*)(kp + 32);
        kx[3] = *(const float4*)(kp + 36);
        #pragma unroll
        for (int cbi = 0; cbi < 2; cbi++) {
            int cb = cb0 + cbi;
            int Lb = ((cb >> 2) << 5) + ((cb & 3) << 2);   // L(cb,0)
            #pragma unroll
            for (int j = 0; j < 8; j++) {
                int L = Lb + ((j >> 2) << 4) + (j & 3);
                vr[cbi][j] = vh[((size_t)(ck * 64 + L)) * D_ + lane];  // coalesced b32
            }
        }
    };

    auto stage = [&](int buf) {
        float ss = kx[0].x*kx[0].x + kx[0].y*kx[0].y + kx[0].z*kx[0].z + kx[0].w*kx[0].w
                 + kx[1].x*kx[1].x + kx[1].y*kx[1].y + kx[1].z*kx[1].z + kx[1].w*kx[1].w
                 + kx[2].x*kx[2].x + kx[2].y*kx[2].y + kx[2].z*kx[2].z + kx[2].w*kx[2].w
                 + kx[3].x*kx[3].x + kx[3].y*kx[3].y + kx[3].z*kx[3].z + kx[3].w*kx[3].w;
        ss += __shfl_xor(ss, 1);       // 4 lanes of same key cover dims 0..63
        ss += __shfl_xor(ss, 2);
        float sc = __ocml_native_rsqrt_f32(ss);
        #pragma unroll
        for (int i = 0; i < 2; i++) {
            float4 a = kx[2 * i], b = kx[2 * i + 1];
            union { unsigned int u[4]; short8 s8; } pk;
            pk.u[0] = pk2(a.x*sc, a.y*sc); pk.u[1] = pk2(a.z*sc, a.w*sc);
            pk.u[2] = pk2(b.x*sc, b.y*sc); pk.u[3] = pk2(b.z*sc, b.w*sc);
            int cbk = (lane & 3) + 4 * i;
            *(short8*)&ks[buf][srow * 64 + ((cbk ^ ksw) << 3)] = pk.s8;   // b128
        }
        #pragma unroll
        for (int cbi = 0; cbi < 2; cbi++) {
            union { unsigned int u[4]; short8 s8; } pv;
            pv.u[0] = pk2(vr[cbi][0], vr[cbi][1]); pv.u[1] = pk2(vr[cbi][2], vr[cbi][3]);
            pv.u[2] = pk2(vr[cbi][4], vr[cbi][5]); pv.u[3] = pk2(vr[cbi][6], vr[cbi][7]);
            *(short8*)&vt[buf][lane * 64 + (((cb0 + cbi) ^ vsw) << 3)] = pv.s8;  // b128
        }
    };

    auto compute = [&](int buf) {
        const unsigned short* ksb = &ks[buf][0];
        const unsigned short* vsb = &vt[buf][0];
        #pragma unroll
        for (int g = 0; g < 2; g++) {
            // ---- S^T for 32 keys: A = K-frag (LDS b128), B = Q-frag (regs) ----
            floatx4 s[4][2];
            #pragma unroll
            for (int s2 = 0; s2 < 2; s2++) {
                int st = g * 2 + s2;
                short8 bk0 = *(const short8*)(ksb + (st * 16 + lam) * 64 + (((0 + quad) ^ sw) << 3));
                short8 bk1 = *(const short8*)(ksb + (st * 16 + lam) * 64 + (((4 + quad) ^ sw) << 3));
                #pragma unroll
                for (int t = 0; t < 4; t++) {
                    floatx4 acc = (floatx4){0.f, 0.f, 0.f, 0.f};
                    acc = __builtin_amdgcn_mfma_f32_16x16x32_bf16(bk0, aq[t][0], acc, 0, 0, 0);
                    acc = __builtin_amdgcn_mfma_f32_16x16x32_bf16(bk1, aq[t][1], acc, 0, 0, 0);
                    s[t][s2] = acc;
                }
            }
            // ---- exp2 + pack: S^T C-layout IS the PV A-fragment layout ----
            short8 pa[4];
            #pragma unroll
            for (int t = 0; t < 4; t++) {
                float e00 = __ocml_native_exp2_f32(s[t][0][0]);
                float e01 = __ocml_native_exp2_f32(s[t][0][1]);
                float e02 = __ocml_native_exp2_f32(s[t][0][2]);
                float e03 = __ocml_native_exp2_f32(s[t][0][3]);
                float e10 = __ocml_native_exp2_f32(s[t][1][0]);
                float e11 = __ocml_native_exp2_f32(s[t][1][1]);
                float e12 = __ocml_native_exp2_f32(s[t][1][2]);
                float e13 = __ocml_native_exp2_f32(s[t][1][3]);
                l[t] += ((e00 + e01) + (e02 + e03)) + ((e10 + e11) + (e12 + e13));
                union { unsigned int u[4]; short8 s8; } pk;
                pk.u[0] = pk2(e00, e01); pk.u[1] = pk2(e02, e03);
                pk.u[2] = pk2(e10, e11); pk.u[3] = pk2(e12, e13);
                pa[t] = pk.s8;
            }
            // ---- PV: B-frag = one b128 from vt (permuted V^T) ----
            #pragma unroll
            for (int dt = 0; dt < 4; dt++) {
                short8 bv = *(const short8*)(vsb + (dt * 16 + lam) * 64 + (((g * 4 + quad) ^ sw) << 3));
                #pragma unroll
                for (int t = 0; t < 4; t++)
                    oacc[t][dt] = __builtin_amdgcn_mfma_f32_16x16x32_bf16(pa[t], bv, oacc[t][dt], 0, 0, 0);
            }
        }
    };

    // ---- software-pipelined chunk loop: 1 barrier per chunk ----
    gload(0);
    stage(0);
    __syncthreads();
    for (int c = 0; c < 16; ++c) {
        int buf = c & 1;
        if (c < 15) gload(c + 1);      // regs prefetch overlaps compute
        compute(buf);
        if (c < 15) stage(buf ^ 1);    // waits on prefetch, writes other buffer
        __syncthreads();
    }

    // ---- epilogue: reduce l across quads, divide, store f32 ----
    const int b = head >> 4, hh = head & 15;
    #pragma unroll
    for (int t = 0; t < 4; t++) {
        float lr = l[t];
        lr += __shfl_xor(lr, 16);
        lr += __shfl_xor(lr, 32);
        float rl = 1.0f / lr;                    // lane lam holds 1/l for query t*16+lam
        float rq[4];
        #pragma unroll
        for (int r = 0; r < 4; r++) rq[r] = __shfl(rl, quad * 4 + r);
        float* ob = out + ((size_t)b * N_ + q0 + t * 16) * (H_ * D_) + hh * 64;
        #pragma unroll
        for (int dt = 0; dt < 4; dt++)
            #pragma unroll
            for (int r = 0; r < 4; r++)
                ob[(quad * 4 + r) * (H_ * D_) + dt * 16 + lam] = oacc[t][dt][r] * rq[r];
    }
}

extern "C" void kernel_launch(void* const* d_in, const int* in_sizes, int n_in,
                              void* d_out, int out_size, void* d_ws, size_t ws_size,
                              hipStream_t stream) {
    const float* q = (const float*)d_in[0];
    const float* k = (const float*)d_in[1];
    const float* v = (const float*)d_in[2];
    float* out = (float*)d_out;
    (void)d_ws; (void)ws_size;
    hipLaunchKernelGGL(attn_fused, dim3(NH_ * 4), dim3(256), 0, stream, q, k, v, out);
}

// Round 6
// 159.056 us; speedup vs baseline: 2.2732x; 1.0340x over previous
//
#include <hip/hip_runtime.h>
#include <stdint.h>

typedef __attribute__((ext_vector_type(8))) short short8;
typedef __attribute__((ext_vector_type(4))) float floatx4;

#define B_   8
#define H_   16
#define N_   1024
#define D_   64
#define NH_  (B_*H_)
#define LOG2E 1.44269504088896340736f

extern "C" {
__device__ float __ocml_native_exp2_f32(float);
__device__ float __ocml_native_rsqrt_f32(float);
}

// pack two f32 -> bf16x2 (round-half-up on magnitude; fine for our ranges)
__device__ __forceinline__ unsigned int pk2(float a, float b) {
    unsigned int ua = __float_as_uint(a) + 0x8000u;
    unsigned int ub = __float_as_uint(b) + 0x8000u;
    return __builtin_amdgcn_perm(ub, ua, 0x07060302);  // (bf(b)<<16)|bf(a)
}

// ---------------------------------------------------------------------------
// Fully fused cosine attention.
// 512 threads = 8 waves; wave = 32 queries (2 m-tiles); block = 256 queries;
// grid = 128 heads * 4 (XCD-swizzled) -> 2 blocks/CU, 16 waves/CU (4/SIMD).
// LDS: stride-64-short rows, XOR swizzle cb^(row&7) on 16B blocks, all
// accesses 16B-aligned b128 (uniform 8 lanes / 16B window = full LDS BW).
//   ks[key][d] : K chunk bf16, row-normalized
//   vt[d][key] : V chunk transposed, key order permuted by
//                L(cb,j) = (cb>>2)*32 + (cb&3)*4 + (j>>2)*16 + (j&3)
// S^T = K.Qn^T via MFMA so exp(S^T) is directly the PV A-fragment.
// ---------------------------------------------------------------------------
__global__ __launch_bounds__(512, 4) void attn_fused(
    const float* __restrict__ q, const float* __restrict__ k,
    const float* __restrict__ v, float* __restrict__ out)
{
    __shared__ __align__(16) unsigned short ks[2][64 * 64];
    __shared__ __align__(16) unsigned short vt[2][64 * 64];

    const int bid = blockIdx.x;
    const int xcd = bid & 7, rest = bid >> 3;
    const int qt = rest & 3;
    const int head = (rest >> 2) * 8 + xcd;    // 4 blocks of a head share an XCD
    const int tid = threadIdx.x, w = tid >> 6, lane = tid & 63;
    const int lam = lane & 15, quad = lane >> 4;
    const int sw = lam & 7;                    // frag-read swizzle key
    const int q0 = qt * 256 + w * 32;          // this wave's 32 queries

    const float* qh = q + ((size_t)head * N_ + q0) * D_;
    const float* kh = k + (size_t)head * N_ * D_;
    const float* vh = v + (size_t)head * N_ * D_;

    // ---- Q: load f32, L2-normalize (x log2e), pack to bf16 B-frags ----
    short8 aq[2][2];
    #pragma unroll
    for (int t = 0; t < 2; t++) {
        const float* qr = qh + (t * 16 + lam) * D_ + quad * 8;
        float4 f0 = *(const float4*)(qr);
        float4 f1 = *(const float4*)(qr + 4);
        float4 f2 = *(const float4*)(qr + 32);
        float4 f3 = *(const float4*)(qr + 36);
        float ss = f0.x*f0.x + f0.y*f0.y + f0.z*f0.z + f0.w*f0.w
                 + f1.x*f1.x + f1.y*f1.y + f1.z*f1.z + f1.w*f1.w
                 + f2.x*f2.x + f2.y*f2.y + f2.z*f2.z + f2.w*f2.w
                 + f3.x*f3.x + f3.y*f3.y + f3.z*f3.z + f3.w*f3.w;
        ss += __shfl_xor(ss, 16);      // 4 quads of same lam cover dims 0..63
        ss += __shfl_xor(ss, 32);
        float sc = LOG2E * __ocml_native_rsqrt_f32(ss);
        union { unsigned int u[4]; short8 s8; } p0, p1;
        p0.u[0] = pk2(f0.x*sc, f0.y*sc); p0.u[1] = pk2(f0.z*sc, f0.w*sc);
        p0.u[2] = pk2(f1.x*sc, f1.y*sc); p0.u[3] = pk2(f1.z*sc, f1.w*sc);
        p1.u[0] = pk2(f2.x*sc, f2.y*sc); p1.u[1] = pk2(f2.z*sc, f2.w*sc);
        p1.u[2] = pk2(f3.x*sc, f3.y*sc); p1.u[3] = pk2(f3.z*sc, f3.w*sc);
        aq[t][0] = p0.s8; aq[t][1] = p1.s8;
    }

    floatx4 oacc[2][4];
    #pragma unroll
    for (int t = 0; t < 2; t++)
        #pragma unroll
        for (int dt = 0; dt < 4; dt++) oacc[t][dt] = (floatx4){0.f, 0.f, 0.f, 0.f};
    float l[2] = {0.f, 0.f};

    // ---- staging maps (512 threads stage one 64-key chunk) ----
    // K: thread owns key-row srow, 8 dims at d-block cbk = lane&7
    const int srow = w * 8 + (lane >> 3);
    const int cbk  = lane & 7;
    const int ksw  = srow & 7;
    // V^T: thread owns d = lane, phys key-block cb = w (8 logical keys)
    const int Lb   = ((w >> 2) << 5) + ((w & 3) << 2);   // L(w, 0)
    const int vwin = (w ^ (lane & 7)) << 3;

    float4 kx[2];
    float  vr[8];

    auto gload = [&](int ck) {
        const float* kp = kh + ((size_t)(ck * 64 + srow)) * D_ + cbk * 8;
        kx[0] = *(const float4*)(kp);
        kx[1] = *(const float4*)(kp + 4);
        #pragma unroll
        for (int j = 0; j < 8; j++) {
            int L = Lb + ((j >> 2) << 4) + (j & 3);
            vr[j] = vh[((size_t)(ck * 64 + L)) * D_ + lane];   // coalesced b32
        }
    };

    auto stage = [&](int buf) {
        float ss = kx[0].x*kx[0].x + kx[0].y*kx[0].y + kx[0].z*kx[0].z + kx[0].w*kx[0].w
                 + kx[1].x*kx[1].x + kx[1].y*kx[1].y + kx[1].z*kx[1].z + kx[1].w*kx[1].w;
        ss += __shfl_xor(ss, 1);       // 8 lanes of same key cover dims 0..63
        ss += __shfl_xor(ss, 2);
        ss += __shfl_xor(ss, 4);
        float sc = __ocml_native_rsqrt_f32(ss);
        union { unsigned int u[4]; short8 s8; } pk;
        pk.u[0] = pk2(kx[0].x*sc, kx[0].y*sc); pk.u[1] = pk2(kx[0].z*sc, kx[0].w*sc);
        pk.u[2] = pk2(kx[1].x*sc, kx[1].y*sc); pk.u[3] = pk2(kx[1].z*sc, kx[1].w*sc);
        *(short8*)&ks[buf][srow * 64 + ((cbk ^ ksw) << 3)] = pk.s8;      // b128
        union { unsigned int u[4]; short8 s8; } pv;
        pv.u[0] = pk2(vr[0], vr[1]); pv.u[1] = pk2(vr[2], vr[3]);
        pv.u[2] = pk2(vr[4], vr[5]); pv.u[3] = pk2(vr[6], vr[7]);
        *(short8*)&vt[buf][lane * 64 + vwin] = pv.s8;                    // b128
    };

    auto compute = [&](int buf) {
        const unsigned short* ksb = &ks[buf][0];
        const unsigned short* vsb = &vt[buf][0];
        #pragma unroll
        for (int g = 0; g < 2; g++) {
            // ---- S^T for 32 keys: A = K-frag (LDS b128), B = Q-frag (regs) ----
            floatx4 s[2][2];
            #pragma unroll
            for (int s2 = 0; s2 < 2; s2++) {
                int st = g * 2 + s2;
                short8 bk0 = *(const short8*)(ksb + (st * 16 + lam) * 64 + (((0 + quad) ^ sw) << 3));
                short8 bk1 = *(const short8*)(ksb + (st * 16 + lam) * 64 + (((4 + quad) ^ sw) << 3));
                #pragma unroll
                for (int t = 0; t < 2; t++) {
                    floatx4 acc = (floatx4){0.f, 0.f, 0.f, 0.f};
                    acc = __builtin_amdgcn_mfma_f32_16x16x32_bf16(bk0, aq[t][0], acc, 0, 0, 0);
                    acc = __builtin_amdgcn_mfma_f32_16x16x32_bf16(bk1, aq[t][1], acc, 0, 0, 0);
                    s[t][s2] = acc;
                }
            }
            // ---- exp2 + pack: S^T C-layout IS the PV A-fragment layout ----
            short8 pa[2];
            #pragma unroll
            for (int t = 0; t < 2; t++) {
                float e00 = __ocml_native_exp2_f32(s[t][0][0]);
                float e01 = __ocml_native_exp2_f32(s[t][0][1]);
                float e02 = __ocml_native_exp2_f32(s[t][0][2]);
                float e03 = __ocml_native_exp2_f32(s[t][0][3]);
                float e10 = __ocml_native_exp2_f32(s[t][1][0]);
                float e11 = __ocml_native_exp2_f32(s[t][1][1]);
                float e12 = __ocml_native_exp2_f32(s[t][1][2]);
                float e13 = __ocml_native_exp2_f32(s[t][1][3]);
                l[t] += ((e00 + e01) + (e02 + e03)) + ((e10 + e11) + (e12 + e13));
                union { unsigned int u[4]; short8 s8; } pk;
                pk.u[0] = pk2(e00, e01); pk.u[1] = pk2(e02, e03);
                pk.u[2] = pk2(e10, e11); pk.u[3] = pk2(e12, e13);
                pa[t] = pk.s8;
            }
            // ---- PV: B-frag = one b128 from vt (permuted V^T) ----
            #pragma unroll
            for (int dt = 0; dt < 4; dt++) {
                short8 bv = *(const short8*)(vsb + (dt * 16 + lam) * 64 + (((g * 4 + quad) ^ sw) << 3));
                #pragma unroll
                for (int t = 0; t < 2; t++)
                    oacc[t][dt] = __builtin_amdgcn_mfma_f32_16x16x32_bf16(pa[t], bv, oacc[t][dt], 0, 0, 0);
            }
        }
    };

    // ---- software-pipelined chunk loop: 1 barrier per chunk ----
    gload(0);
    stage(0);
    __syncthreads();
    for (int c = 0; c < 16; ++c) {
        int buf = c & 1;
        if (c < 15) gload(c + 1);      // regs prefetch overlaps compute
        compute(buf);
        if (c < 15) stage(buf ^ 1);    // waits on prefetch, writes other buffer
        __syncthreads();
    }

    // ---- epilogue: reduce l across quads, divide, store f32 ----
    const int b = head >> 4, hh = head & 15;
    #pragma unroll
    for (int t = 0; t < 2; t++) {
        float lr = l[t];
        lr += __shfl_xor(lr, 16);
        lr += __shfl_xor(lr, 32);
        float rl = 1.0f / lr;                    // lane lam holds 1/l for query t*16+lam
        float rq[4];
        #pragma unroll
        for (int r = 0; r < 4; r++) rq[r] = __shfl(rl, quad * 4 + r);
        float* ob = out + ((size_t)b * N_ + q0 + t * 16) * (H_ * D_) + hh * 64;
        #pragma unroll
        for (int dt = 0; dt < 4; dt++)
            #pragma unroll
            for (int r = 0; r < 4; r++)
                ob[(quad * 4 + r) * (H_ * D_) + dt * 16 + lam] = oacc[t][dt][r] * rq[r];
    }
}

extern "C" void kernel_launch(void* const* d_in, const int* in_sizes, int n_in,
                              void* d_out, int out_size, void* d_ws, size_t ws_size,
                              hipStream_t stream) {
    const float* q = (const float*)d_in[0];
    const float* k = (const float*)d_in[1];
    const float* v = (const float*)d_in[2];
    float* out = (float*)d_out;
    (void)d_ws; (void)ws_size;
    hipLaunchKernelGGL(attn_fused, dim3(NH_ * 4), dim3(512), 0, stream, q, k, v, out);
}